// Round 14
// baseline (223.026 us; speedup 1.0000x reference)
//
#include <hip/hip_runtime.h>

typedef unsigned short u16;
typedef unsigned int   u32;

using bf16x8 = __attribute__((ext_vector_type(8))) __bf16;
using u16x8  = __attribute__((ext_vector_type(8))) unsigned short;
using f32x4  = __attribute__((ext_vector_type(4))) float;
using f32x16 = __attribute__((ext_vector_type(16))) float;

#define MFMA16(a, b, c) __builtin_amdgcn_mfma_f32_16x16x32_bf16((a), (b), (c), 0, 0, 0)
#define MFMA32(a, b, c) __builtin_amdgcn_mfma_f32_32x32x16_bf16((a), (b), (c), 0, 0, 0)

__device__ inline u16 f2bf(float f) {
  u32 x = __float_as_uint(f);
  return (u16)((x + 0x7FFFu + ((x >> 16) & 1u)) >> 16);
}

__device__ inline const bf16x8* bfp(const u16* p) {
  return reinterpret_cast<const bf16x8*>(p);
}

// ---------------------------------------------------------------------------
// K01: merged pre-pass. Blocks 0..511: LN1 + transpose (x -> tokens + ln).
// Blocks 512..1023: weight transpose+convert to bf16 W^T.
__global__ __launch_bounds__(256) void k_pre(
    const float* __restrict__ x, const float* __restrict__ g1,
    const float* __restrict__ b1, float* __restrict__ tokens,
    u16* __restrict__ ln,
    const float* __restrict__ Wqkv, const float* __restrict__ Wp,
    const float* __restrict__ W1,   const float* __restrict__ W2,
    u16* __restrict__ wqkvT, u16* __restrict__ wpT,
    u16* __restrict__ w1T,   u16* __restrict__ w2T) {
  __shared__ float tile[256][33];
  __shared__ float red[2][8][32];
  __shared__ float stat[2][32];
  int tid = threadIdx.x;
  if (blockIdx.x >= 512) {
    int blk = blockIdx.x - 512;
    const float* src; u16* dst; int R, C, t;
    if (blk < 192)      { src = Wqkv; dst = wqkvT; R = 256; C = 768; t = blk; }
    else if (blk < 256) { src = Wp;   dst = wpT;   R = 256; C = 256; t = blk - 192; }
    else if (blk < 384) { src = W1;   dst = w1T;   R = 256; C = 512; t = blk - 256; }
    else                { src = W2;   dst = w2T;   R = 512; C = 256; t = blk - 384; }
    int tpc = C >> 5;
    int tr = (t / tpc) << 5, tc = (t % tpc) << 5;
    int j = tid & 31, iq = tid >> 5;
    #pragma unroll
    for (int i = 0; i < 4; ++i)
      tile[iq + 8 * i][j] = src[(size_t)(tr + iq + 8 * i) * C + tc + j];
    __syncthreads();
    #pragma unroll
    for (int i = 0; i < 4; ++i)
      dst[(size_t)(tc + iq + 8 * i) * R + tr + j] = f2bf(tile[j][iq + 8 * i]);
    return;
  }
  int blk = blockIdx.x;
  int b = blk >> 7, n0 = (blk & 127) << 5;
  {
    int cq = tid >> 5, j = tid & 31;
    const float* xp = x + (((size_t)b * 256) << 12) + n0 + j;
    #pragma unroll 8
    for (int it = 0; it < 32; ++it) {
      int c = it * 8 + cq;
      tile[c][j] = xp[(size_t)c << 12];
    }
  }
  __syncthreads();
  {
    int tn = tid & 31, qq = tid >> 5;
    float s = 0.f, s2 = 0.f;
    #pragma unroll 8
    for (int i = 0; i < 32; ++i) {
      float v = tile[qq * 32 + i][tn];
      s += v; s2 += v * v;
    }
    red[0][qq][tn] = s; red[1][qq][tn] = s2;
  }
  __syncthreads();
  if (tid < 32) {
    float su = 0.f, sq = 0.f;
    #pragma unroll
    for (int qq = 0; qq < 8; ++qq) { su += red[0][qq][tid]; sq += red[1][qq][tid]; }
    float mu  = su * (1.f / 256.f);
    float var = sq * (1.f / 256.f) - mu * mu;
    stat[0][tid] = mu;
    stat[1][tid] = rsqrtf(var + 1e-5f);
  }
  __syncthreads();
  float g = g1[tid], bb = b1[tid];
  size_t base = ((size_t)(b * 4096 + n0)) * 256 + tid;
  for (int it = 0; it < 32; ++it) {
    float v = tile[tid][it];
    float y = (v - stat[0][it]) * stat[1][it] * g + bb;
    tokens[base + (size_t)it * 256] = v;
    ln[base + (size_t)it * 256] = f2bf(y);
  }
}

// ---------------------------------------------------------------------------
// GEMM cores. C[m][n] = sum_k A[m][k] * BT[n][k], both bf16 row-major.
template <int K>
__device__ inline void mm16(const u16* __restrict__ A, const u16* __restrict__ BT,
                            int arow, int bcol, f32x4 acc[4]) {
  int lane = threadIdx.x & 63;
  int r = lane & 15, g = lane >> 4;
  const u16* ap  = A  + (size_t)(arow + r) * K + g * 8;
  const u16* bp0 = BT + (size_t)(bcol + r) * K + g * 8;
  #pragma unroll 4
  for (int k0 = 0; k0 < K; k0 += 32) {
    bf16x8 a = *bfp(ap + k0);
    #pragma unroll
    for (int nt = 0; nt < 4; ++nt) {
      bf16x8 b = *bfp(bp0 + nt * 16 * K + k0);
      acc[nt] = MFMA16(a, b, acc[nt]);
    }
  }
}

// 32 rows/wave: shared B-frags, 8 MFMAs per 6 loads.
template <int K>
__device__ inline void mm32(const u16* __restrict__ A, const u16* __restrict__ BT,
                            int arow, int bcol, f32x4 acc[2][4]) {
  int lane = threadIdx.x & 63;
  int r = lane & 15, g = lane >> 4;
  const u16* ap0 = A  + (size_t)(arow + r) * K + g * 8;
  const u16* bp0 = BT + (size_t)(bcol + r) * K + g * 8;
  #pragma unroll 4
  for (int k0 = 0; k0 < K; k0 += 32) {
    bf16x8 a0 = *bfp(ap0 + k0);
    bf16x8 a1 = *bfp(ap0 + 16 * K + k0);
    #pragma unroll
    for (int nt = 0; nt < 4; ++nt) {
      bf16x8 b = *bfp(bp0 + nt * 16 * K + k0);
      acc[0][nt] = MFMA16(a0, b, acc[0][nt]);
      acc[1][nt] = MFMA16(a1, b, acc[1][nt]);
    }
  }
}

// K2: QKV = ln1 @ WqkvT. 32 rows/wave (128 rows/block). Block-uniform output
// type (bx 0-3 = Q, 4-7 = K, 8-11 = V). Q/K go through an LDS transpose so
// global stores are coalesced 16B (K: fully contiguous 1KB/wave-store).
// Q -> q[bh][n][d] (pre-scaled by scale*log2e); K -> kfrag A-order; V -> vfrag.
__global__ __launch_bounds__(256) void k_qkv(
    const u16* __restrict__ ln, const u16* __restrict__ wT,
    u16* __restrict__ q, u16* __restrict__ kf, u16* __restrict__ vf) {
  __shared__ u16 tileT[64][136];   // [col][row], padded: ushort4-aligned, 2-way banks
  int tid = threadIdx.x;
  int w = tid >> 6, lane = tid & 63;
  int r16 = lane & 15, g4 = lane >> 4;
  int m0 = blockIdx.y * 128 + w * 32;
  int bx = blockIdx.x;
  int n0 = bx * 64;
  f32x4 z = {0.f, 0.f, 0.f, 0.f};
  f32x4 acc[2][4] = {{z, z, z, z}, {z, z, z, z}};
  mm32<256>(ln, wT, m0, n0, acc);
  int b = blockIdx.y >> 5;
  const float qsc = (float)(0.17677669529663687 * 1.4426950408889634);

  if (bx >= 8) {
    // ---- V path: direct ushort4 stores into vfrag (unchanged from R13)
    #pragma unroll
    for (int rg = 0; rg < 2; ++rg) {
      int nbase = (m0 & 4095) + rg * 16 + g4 * 4;
      #pragma unroll
      for (int nt = 0; nt < 4; ++nt) {
        int col = n0 + nt * 16 + r16;
        int h = (col >> 5) & 7, d = col & 31;
        size_t bh_off = ((size_t)(b * 8 + h)) << 17;
        int kk = nbase & 31;
        int sel = kk >> 4, lh = (kk >> 3) & 1, j0 = kk & 7;
        ushort4 o4;
        o4.x = f2bf(acc[rg][nt][0]); o4.y = f2bf(acc[rg][nt][1]);
        o4.z = f2bf(acc[rg][nt][2]); o4.w = f2bf(acc[rg][nt][3]);
        *(ushort4*)(vf + bh_off + (size_t)(nbase >> 5) * 1024 + sel * 512 +
                    ((d | (lh << 5)) << 3) + j0) = o4;
      }
    }
    return;
  }

  // ---- Q/K: stage transposed tile in LDS (ushort4 writes: 4 consecutive rows)
  float sc = (bx < 4) ? qsc : 1.0f;
  #pragma unroll
  for (int rg = 0; rg < 2; ++rg) {
    #pragma unroll
    for (int nt = 0; nt < 4; ++nt) {
      ushort4 t4;
      t4.x = f2bf(acc[rg][nt][0] * sc);
      t4.y = f2bf(acc[rg][nt][1] * sc);
      t4.z = f2bf(acc[rg][nt][2] * sc);
      t4.w = f2bf(acc[rg][nt][3] * sc);
      *(ushort4*)&tileT[nt * 16 + r16][w * 32 + rg * 16 + g4 * 4] = t4;
    }
  }
  __syncthreads();

  if (bx < 4) {
    // Q: q[bh][n][0..32), bh = b*8 + bx*2 + hl. 16B stores, 64B row stride.
    int hl = tid >> 7, nl = tid & 127;
    size_t bh_off = ((size_t)(b * 8 + bx * 2 + hl)) << 17;
    int nwb = (blockIdx.y & 31) * 128 + nl;
    u16* dst = q + bh_off + (size_t)nwb * 32;
    #pragma unroll
    for (int i = 0; i < 4; ++i) {
      int d0 = i * 8;
      union { u16 s[8]; u16x8 v; } pk;
      #pragma unroll
      for (int j = 0; j < 8; ++j) pk.s[j] = tileT[hl * 32 + d0 + j][nl];
      *(u16x8*)(dst + d0) = pk.v;
    }
  } else {
    // K: kfrag[bh][chunk][sel][lane][8] — fully coalesced 1KB per wave-store.
    int l = tid & 63;
    #pragma unroll
    for (int i = 0; i < 4; ++i) {
      int u = (tid >> 6) + i * 4;          // 16 units: hl(2) x chunk(4) x sel(2)
      int hl = u >> 3, chunk = (u >> 1) & 3, sel = u & 1;
      size_t bh_off = ((size_t)(b * 8 + (bx - 4) * 2 + hl)) << 17;
      int gchunk = (blockIdx.y & 31) * 4 + chunk;
      union { u16 s[8]; u16x8 v; } pk;
      #pragma unroll
      for (int j = 0; j < 8; ++j)
        pk.s[j] = tileT[hl * 32 + sel * 16 + (l >> 5) * 8 + j][chunk * 32 + (l & 31)];
      *(u16x8*)(kf + bh_off + (size_t)gchunk * 1024 + sel * 512 + l * 8) = pk.v;
    }
  }
}

// ---------------------------------------------------------------------------
// K3: attention (best-measured R10 form, frozen). 1024 blocks, 512 thr =
// 2 q-subtiles(64 q) x 4 KV-quarters; XCD-locality remap; builtin exp2;
// VALU tree row-sum; two-round LDS 4-way combine.
__global__ __launch_bounds__(512, 4) void k_attn(
    const u16* __restrict__ q, const u16* __restrict__ kf,
    const u16* __restrict__ vf, u16* __restrict__ attnout) {
  __shared__ float obuf[2][3][64][17];
  __shared__ float lsbuf[2][3][64];
  int lane = threadIdx.x & 63;
  int w = threadIdx.x >> 6;
  int qi = w >> 2, kj = w & 3;
  int r32 = lane & 31, hi = lane >> 5;
  int d = blockIdx.x;
  int bh = (d & 7) + 8 * (d >> 8);
  int qt = (d >> 3) & 31;
  int q0 = qt * 128 + qi * 64;
  const u16* qh = q + ((size_t)bh << 17);
  bf16x8 qf00 = *bfp(qh + (size_t)(q0 + r32) * 32 + hi * 8);
  bf16x8 qf01 = *bfp(qh + (size_t)(q0 + r32) * 32 + 16 + hi * 8);
  bf16x8 qf10 = *bfp(qh + (size_t)(q0 + 32 + r32) * 32 + hi * 8);
  bf16x8 qf11 = *bfp(qh + (size_t)(q0 + 32 + r32) * 32 + 16 + hi * 8);

  const u16* kp = kf + ((size_t)bh << 17) + (size_t)kj * 32768 + lane * 8;
  const u16* vp = vf + ((size_t)bh << 17) + (size_t)kj * 32768 + lane * 8;

  f32x16 o0, o1, zz;
  #pragma unroll
  for (int r = 0; r < 16; ++r) { o0[r] = 0.f; o1[r] = 0.f; zz[r] = 0.f; }
  float ls0 = 0.f, ls1 = 0.f;

  #pragma unroll 2
  for (int c = 0; c < 32; ++c) {
    bf16x8 ka0 = *bfp(kp);
    bf16x8 ka1 = *bfp(kp + 512);
    bf16x8 va0 = *bfp(vp);
    bf16x8 va1 = *bfp(vp + 512);
    kp += 1024; vp += 1024;

    // ---- q-group 0
    {
      f32x16 s = MFMA32(ka0, qf00, zz);
      s = MFMA32(ka1, qf01, s);
      #pragma unroll
      for (int r = 0; r < 16; ++r) s[r] = __builtin_amdgcn_exp2f(s[r]);
      float t0 = ((s[0] + s[1]) + (s[2] + s[3])) + ((s[4] + s[5]) + (s[6] + s[7]));
      float t1 = ((s[8] + s[9]) + (s[10] + s[11])) + ((s[12] + s[13]) + (s[14] + s[15]));
      ls0 += t0 + t1;
      u32 c8[8];
      #pragma unroll
      for (int i = 0; i < 8; ++i)
        asm("v_cvt_pk_bf16_f32 %0, %1, %2" : "=v"(c8[i]) : "v"(s[2 * i]), "v"(s[2 * i + 1]));
      asm("v_permlane32_swap_b32 %0, %1" : "+v"(c8[0]), "+v"(c8[2]));
      asm("v_permlane32_swap_b32 %0, %1" : "+v"(c8[1]), "+v"(c8[3]));
      asm("v_permlane32_swap_b32 %0, %1" : "+v"(c8[4]), "+v"(c8[6]));
      asm("v_permlane32_swap_b32 %0, %1" : "+v"(c8[5]), "+v"(c8[7]));
      union { u32 u[4]; bf16x8 v; } pf0, pf1;
      pf0.u[0] = c8[0]; pf0.u[1] = c8[1]; pf0.u[2] = c8[2]; pf0.u[3] = c8[3];
      pf1.u[0] = c8[4]; pf1.u[1] = c8[5]; pf1.u[2] = c8[6]; pf1.u[3] = c8[7];
      o0 = MFMA32(va0, pf0.v, o0);
      o0 = MFMA32(va1, pf1.v, o0);
    }
    // ---- q-group 1
    {
      f32x16 s = MFMA32(ka0, qf10, zz);
      s = MFMA32(ka1, qf11, s);
      #pragma unroll
      for (int r = 0; r < 16; ++r) s[r] = __builtin_amdgcn_exp2f(s[r]);
      float t0 = ((s[0] + s[1]) + (s[2] + s[3])) + ((s[4] + s[5]) + (s[6] + s[7]));
      float t1 = ((s[8] + s[9]) + (s[10] + s[11])) + ((s[12] + s[13]) + (s[14] + s[15]));
      ls1 += t0 + t1;
      u32 c8[8];
      #pragma unroll
      for (int i = 0; i < 8; ++i)
        asm("v_cvt_pk_bf16_f32 %0, %1, %2" : "=v"(c8[i]) : "v"(s[2 * i]), "v"(s[2 * i + 1]));
      asm("v_permlane32_swap_b32 %0, %1" : "+v"(c8[0]), "+v"(c8[2]));
      asm("v_permlane32_swap_b32 %0, %1" : "+v"(c8[1]), "+v"(c8[3]));
      asm("v_permlane32_swap_b32 %0, %1" : "+v"(c8[4]), "+v"(c8[6]));
      asm("v_permlane32_swap_b32 %0, %1" : "+v"(c8[5]), "+v"(c8[7]));
      union { u32 u[4]; bf16x8 v; } pf0, pf1;
      pf0.u[0] = c8[0]; pf0.u[1] = c8[1]; pf0.u[2] = c8[2]; pf0.u[3] = c8[3];
      pf1.u[0] = c8[4]; pf1.u[1] = c8[5]; pf1.u[2] = c8[6]; pf1.u[3] = c8[7];
      o1 = MFMA32(va0, pf0.v, o1);
      o1 = MFMA32(va1, pf1.v, o1);
    }
  }

  ls0 += __shfl_xor(ls0, 32);
  ls1 += __shfl_xor(ls1, 32);

  if (kj != 0) {
    #pragma unroll
    for (int g = 0; g < 16; ++g) obuf[qi][kj - 1][lane][g] = o0[g];
    lsbuf[qi][kj - 1][lane] = ls0;
  }
  __syncthreads();
  float inv0 = 0.f;
  if (kj == 0) {
    float lst = ls0 + lsbuf[qi][0][lane] + lsbuf[qi][1][lane] + lsbuf[qi][2][lane];
    inv0 = __builtin_amdgcn_rcpf(lst);
    #pragma unroll
    for (int g = 0; g < 16; ++g)
      o0[g] += obuf[qi][0][lane][g] + obuf[qi][1][lane][g] + obuf[qi][2][lane][g];
  }
  __syncthreads();
  if (kj != 0) {
    #pragma unroll
    for (int g = 0; g < 16; ++g) obuf[qi][kj - 1][lane][g] = o1[g];
    lsbuf[qi][kj - 1][lane] = ls1;
  }
  __syncthreads();
  if (kj == 0) {
    int b = bh >> 3, h = bh & 7;
    float lst1 = ls1 + lsbuf[qi][0][lane] + lsbuf[qi][1][lane] + lsbuf[qi][2][lane];
    float inv1 = __builtin_amdgcn_rcpf(lst1);
    #pragma unroll
    for (int g = 0; g < 16; ++g)
      o1[g] += obuf[qi][0][lane][g] + obuf[qi][1][lane][g] + obuf[qi][2][lane][g];
    size_t nrow0 = ((size_t)(b * 4096 + q0 + r32)) * 256 + h * 32;
    size_t nrow1 = ((size_t)(b * 4096 + q0 + 32 + r32)) * 256 + h * 32;
    #pragma unroll
    for (int g = 0; g < 4; ++g) {
      ushort4 ov;
      ov.x = f2bf(o0[g * 4 + 0] * inv0);
      ov.y = f2bf(o0[g * 4 + 1] * inv0);
      ov.z = f2bf(o0[g * 4 + 2] * inv0);
      ov.w = f2bf(o0[g * 4 + 3] * inv0);
      *(ushort4*)(attnout + nrow0 + g * 8 + hi * 4) = ov;
      ushort4 ow;
      ow.x = f2bf(o1[g * 4 + 0] * inv1);
      ow.y = f2bf(o1[g * 4 + 1] * inv1);
      ow.z = f2bf(o1[g * 4 + 2] * inv1);
      ow.w = f2bf(o1[g * 4 + 3] * inv1);
      *(ushort4*)(attnout + nrow1 + g * 8 + hi * 4) = ow;
    }
  }
}

// ---------------------------------------------------------------------------
// K4: fused post-pass, 16-row blocks (1024 blocks = 4/CU for 2x TLP).
// Stage A: proj+residual+LN2 (wave w -> 32 cols); tokens2 stays in regs.
// Stage B: h = gelu(ln2 @ W1T) (wave w -> 64 cols) via LDS ln2.
// Stage C: out = tokens2 + h @ W2T (wave w -> same 32 cols as A), transposed.
__global__ __launch_bounds__(512) void k_post(
    const u16* __restrict__ ao, const u16* __restrict__ wpT,
    const float* __restrict__ bp, const float* __restrict__ g2,
    const float* __restrict__ b2, const float* __restrict__ tokens,
    const u16* __restrict__ w1T, const float* __restrict__ bf1,
    const u16* __restrict__ w2T, const float* __restrict__ bf2,
    float* __restrict__ out) {
  __shared__ u16 lnS[16][264];
  __shared__ u16 hS[16][520];
  __shared__ float red[2][8][16];
  int w = threadIdx.x >> 6, lane = threadIdx.x & 63;
  int r16 = lane & 15, g4 = lane >> 4;
  int m0 = blockIdx.x * 16;
  f32x4 z = {0.f, 0.f, 0.f, 0.f};

  // ---- stage A: proj + residual + LN2 (2 col-tiles per wave)
  f32x4 tA[2] = {z, z};
  {
    const u16* ap = ao  + (size_t)(m0 + r16) * 256 + g4 * 8;
    const u16* bp0 = wpT + (size_t)(w * 32 + r16) * 256 + g4 * 8;
    #pragma unroll 4
    for (int k0 = 0; k0 < 256; k0 += 32) {
      bf16x8 a = *bfp(ap + k0);
      bf16x8 b0 = *bfp(bp0 + k0);
      bf16x8 b1 = *bfp(bp0 + 16 * 256 + k0);
      tA[0] = MFMA16(a, b0, tA[0]);
      tA[1] = MFMA16(a, b1, tA[1]);
    }
  }
  float sum[4] = {0.f, 0.f, 0.f, 0.f}, sq[4] = {0.f, 0.f, 0.f, 0.f};
  #pragma unroll
  for (int nt = 0; nt < 2; ++nt) {
    int col = w * 32 + nt * 16 + r16;
    float bias = bp[col];
    #pragma unroll
    for (int r = 0; r < 4; ++r) {
      float v = tokens[(size_t)(m0 + g4 * 4 + r) * 256 + col] + tA[nt][r] + bias;
      tA[nt][r] = v;
      sum[r] += v; sq[r] += v * v;
    }
  }
  #pragma unroll
  for (int mask = 1; mask < 16; mask <<= 1) {
    #pragma unroll
    for (int r = 0; r < 4; ++r) {
      sum[r] += __shfl_xor(sum[r], mask);
      sq[r]  += __shfl_xor(sq[r], mask);
    }
  }
  if (r16 == 0) {
    #pragma unroll
    for (int r = 0; r < 4; ++r) {
      red[0][w][g4 * 4 + r] = sum[r];
      red[1][w][g4 * 4 + r] = sq[r];
    }
  }
  __syncthreads();
  {
    float mu[4], rs[4];
    #pragma unroll
    for (int r = 0; r < 4; ++r) {
      int ri = g4 * 4 + r;
      float S = 0.f, SQ = 0.f;
      #pragma unroll
      for (int w2 = 0; w2 < 8; ++w2) { S += red[0][w2][ri]; SQ += red[1][w2][ri]; }
      mu[r] = S * (1.f / 256.f);
      rs[r] = rsqrtf(SQ * (1.f / 256.f) - mu[r] * mu[r] + 1e-5f);
    }
    #pragma unroll
    for (int nt = 0; nt < 2; ++nt) {
      int col = w * 32 + nt * 16 + r16;
      float gg = g2[col], bb = b2[col];
      #pragma unroll
      for (int r = 0; r < 4; ++r)
        lnS[g4 * 4 + r][col] = f2bf((tA[nt][r] - mu[r]) * rs[r] * gg + bb);
    }
  }
  __syncthreads();

  // ---- stage B: h = gelu(ln2 @ W1T + bf1): wave w -> cols w*64..+64
  {
    f32x4 accB[4] = {z, z, z, z};
    const u16* apB = &lnS[r16][g4 * 8];
    const u16* bpB = w1T + (size_t)(w * 64 + r16) * 256 + g4 * 8;
    #pragma unroll 4
    for (int k0 = 0; k0 < 256; k0 += 32) {
      bf16x8 a = *bfp(apB + k0);
      #pragma unroll
      for (int nt = 0; nt < 4; ++nt) {
        bf16x8 b = *bfp(bpB + nt * 16 * 256 + k0);
        accB[nt] = MFMA16(a, b, accB[nt]);
      }
    }
    #pragma unroll
    for (int nt = 0; nt < 4; ++nt) {
      int col = w * 64 + nt * 16 + r16;
      float bias = bf1[col];
      #pragma unroll
      for (int r = 0; r < 4; ++r) {
        float xx = accB[nt][r] + bias;
        float x2 = xx * xx;
        float zt = xx * (2.3021188f + 0.10293855f * x2);
        float e  = __builtin_amdgcn_exp2f(zt);
        float ge = xx * (1.f - __builtin_amdgcn_rcpf(1.f + e));
        hS[g4 * 4 + r][col] = f2bf(ge);
      }
    }
  }
  __syncthreads();

  // ---- stage C: out = tokens2 + h @ W2T + bf2 (same 32 cols as stage A)
  {
    f32x4 accC[2] = {z, z};
    const u16* apC = &hS[r16][g4 * 8];
    const u16* bpC = w2T + (size_t)(w * 32 + r16) * 512 + g4 * 8;
    #pragma unroll 4
    for (int k0 = 0; k0 < 512; k0 += 32) {
      bf16x8 a = *bfp(apC + k0);
      bf16x8 b0 = *bfp(bpC + k0);
      bf16x8 b1 = *bfp(bpC + 16 * 512 + k0);
      accC[0] = MFMA16(a, b0, accC[0]);
      accC[1] = MFMA16(a, b1, accC[1]);
    }
    int b = m0 >> 12;
    int nl = (m0 & 4095) + g4 * 4;
    #pragma unroll
    for (int nt = 0; nt < 2; ++nt) {
      int col = w * 32 + nt * 16 + r16;
      float bias = bf2[col];
      float4 o;
      o.x = tA[nt][0] + accC[nt][0] + bias;
      o.y = tA[nt][1] + accC[nt][1] + bias;
      o.z = tA[nt][2] + accC[nt][2] + bias;
      o.w = tA[nt][3] + accC[nt][3] + bias;
      *(float4*)(out + (((size_t)(b * 256 + col)) << 12) + nl) = o;
    }
  }
}

// ---------------------------------------------------------------------------
extern "C" void kernel_launch(void* const* d_in, const int* in_sizes, int n_in,
                              void* d_out, int out_size, void* d_ws, size_t ws_size,
                              hipStream_t stream) {
  (void)in_sizes; (void)n_in; (void)out_size; (void)ws_size;
  const float* x    = (const float*)d_in[0];
  const float* g1   = (const float*)d_in[1];
  const float* b1   = (const float*)d_in[2];
  const float* Wqkv = (const float*)d_in[3];
  const float* Wp   = (const float*)d_in[4];
  const float* bp   = (const float*)d_in[5];
  const float* g2   = (const float*)d_in[6];
  const float* b2   = (const float*)d_in[7];
  const float* W1   = (const float*)d_in[8];
  const float* bf1  = (const float*)d_in[9];
  const float* W2   = (const float*)d_in[10];
  const float* bf2  = (const float*)d_in[11];
  float* out = (float*)d_out;

  char* ws = (char*)d_ws;
  float* tokens = (float*)(ws);                  // 16,777,216 B
  u16* lnb      = (u16*)(ws + 16777216);         //  8,388,608 B (ln1)
  u16* qb       = (u16*)(ws + 25165824);         //  8,388,608 B
  u16* kfb      = (u16*)(ws + 33554432);         //  8,388,608 B (K fragments)
  u16* vfb      = (u16*)(ws + 41943040);         //  8,388,608 B (V fragments)
  u16* aob      = (u16*)(ws + 50331648);         //  8,388,608 B (attnout)
  u16* wqkvT    = (u16*)(ws + 67108864);         //    393,216 B
  u16* wpT      = (u16*)(ws + 67502080);         //    131,072 B
  u16* w1T      = (u16*)(ws + 67633152);         //    262,144 B
  u16* w2T      = (u16*)(ws + 67895296);         //    262,144 B

  k_pre  <<<1024, 256, 0, stream>>>(x, g1, b1, tokens, lnb,
                                    Wqkv, Wp, W1, W2, wqkvT, wpT, w1T, w2T);
  k_qkv  <<<dim3(12, 128), 256, 0, stream>>>(lnb, wqkvT, qb, kfb, vfb);
  k_attn <<<1024, 512, 0, stream>>>(qb, kfb, vfb, aob);
  k_post <<<1024, 512, 0, stream>>>(aob, wpT, bp, g2, b2, tokens,
                                    w1T, bf1, w2T, bf2, out);
}

// Round 15
// 216.743 us; speedup vs baseline: 1.0290x; 1.0290x over previous
//
#include <hip/hip_runtime.h>

typedef unsigned short u16;
typedef unsigned int   u32;

using bf16x8 = __attribute__((ext_vector_type(8))) __bf16;
using f32x4  = __attribute__((ext_vector_type(4))) float;
using f32x16 = __attribute__((ext_vector_type(16))) float;

#define MFMA16(a, b, c) __builtin_amdgcn_mfma_f32_16x16x32_bf16((a), (b), (c), 0, 0, 0)
#define MFMA32(a, b, c) __builtin_amdgcn_mfma_f32_32x32x16_bf16((a), (b), (c), 0, 0, 0)

__device__ inline u16 f2bf(float f) {
  u32 x = __float_as_uint(f);
  return (u16)((x + 0x7FFFu + ((x >> 16) & 1u)) >> 16);
}

__device__ inline const bf16x8* bfp(const u16* p) {
  return reinterpret_cast<const bf16x8*>(p);
}

// ---------------------------------------------------------------------------
// K01: merged pre-pass. Blocks 0..511: LN1 + transpose (x -> tokens + ln).
// Blocks 512..1023: weight transpose+convert to bf16 W^T.
__global__ __launch_bounds__(256) void k_pre(
    const float* __restrict__ x, const float* __restrict__ g1,
    const float* __restrict__ b1, float* __restrict__ tokens,
    u16* __restrict__ ln,
    const float* __restrict__ Wqkv, const float* __restrict__ Wp,
    const float* __restrict__ W1,   const float* __restrict__ W2,
    u16* __restrict__ wqkvT, u16* __restrict__ wpT,
    u16* __restrict__ w1T,   u16* __restrict__ w2T) {
  __shared__ float tile[256][33];
  __shared__ float red[2][8][32];
  __shared__ float stat[2][32];
  int tid = threadIdx.x;
  if (blockIdx.x >= 512) {
    int blk = blockIdx.x - 512;
    const float* src; u16* dst; int R, C, t;
    if (blk < 192)      { src = Wqkv; dst = wqkvT; R = 256; C = 768; t = blk; }
    else if (blk < 256) { src = Wp;   dst = wpT;   R = 256; C = 256; t = blk - 192; }
    else if (blk < 384) { src = W1;   dst = w1T;   R = 256; C = 512; t = blk - 256; }
    else                { src = W2;   dst = w2T;   R = 512; C = 256; t = blk - 384; }
    int tpc = C >> 5;
    int tr = (t / tpc) << 5, tc = (t % tpc) << 5;
    int j = tid & 31, iq = tid >> 5;
    #pragma unroll
    for (int i = 0; i < 4; ++i)
      tile[iq + 8 * i][j] = src[(size_t)(tr + iq + 8 * i) * C + tc + j];
    __syncthreads();
    #pragma unroll
    for (int i = 0; i < 4; ++i)
      dst[(size_t)(tc + iq + 8 * i) * R + tr + j] = f2bf(tile[j][iq + 8 * i]);
    return;
  }
  int blk = blockIdx.x;
  int b = blk >> 7, n0 = (blk & 127) << 5;
  {
    int cq = tid >> 5, j = tid & 31;
    const float* xp = x + (((size_t)b * 256) << 12) + n0 + j;
    #pragma unroll 8
    for (int it = 0; it < 32; ++it) {
      int c = it * 8 + cq;
      tile[c][j] = xp[(size_t)c << 12];
    }
  }
  __syncthreads();
  {
    int tn = tid & 31, qq = tid >> 5;
    float s = 0.f, s2 = 0.f;
    #pragma unroll 8
    for (int i = 0; i < 32; ++i) {
      float v = tile[qq * 32 + i][tn];
      s += v; s2 += v * v;
    }
    red[0][qq][tn] = s; red[1][qq][tn] = s2;
  }
  __syncthreads();
  if (tid < 32) {
    float su = 0.f, sq = 0.f;
    #pragma unroll
    for (int qq = 0; qq < 8; ++qq) { su += red[0][qq][tid]; sq += red[1][qq][tid]; }
    float mu  = su * (1.f / 256.f);
    float var = sq * (1.f / 256.f) - mu * mu;
    stat[0][tid] = mu;
    stat[1][tid] = rsqrtf(var + 1e-5f);
  }
  __syncthreads();
  float g = g1[tid], bb = b1[tid];
  size_t base = ((size_t)(b * 4096 + n0)) * 256 + tid;
  for (int it = 0; it < 32; ++it) {
    float v = tile[tid][it];
    float y = (v - stat[0][it]) * stat[1][it] * g + bb;
    tokens[base + (size_t)it * 256] = v;
    ln[base + (size_t)it * 256] = f2bf(y);
  }
}

// ---------------------------------------------------------------------------
// GEMM cores. C[m][n] = sum_k A[m][k] * BT[n][k], both bf16 row-major.
template <int K>
__device__ inline void mm16(const u16* __restrict__ A, const u16* __restrict__ BT,
                            int arow, int bcol, f32x4 acc[4]) {
  int lane = threadIdx.x & 63;
  int r = lane & 15, g = lane >> 4;
  const u16* ap  = A  + (size_t)(arow + r) * K + g * 8;
  const u16* bp0 = BT + (size_t)(bcol + r) * K + g * 8;
  #pragma unroll 4
  for (int k0 = 0; k0 < K; k0 += 32) {
    bf16x8 a = *bfp(ap + k0);
    #pragma unroll
    for (int nt = 0; nt < 4; ++nt) {
      bf16x8 b = *bfp(bp0 + nt * 16 * K + k0);
      acc[nt] = MFMA16(a, b, acc[nt]);
    }
  }
}

// 32 rows/wave: shared B-frags, 8 MFMAs per 6 loads.
template <int K>
__device__ inline void mm32(const u16* __restrict__ A, const u16* __restrict__ BT,
                            int arow, int bcol, f32x4 acc[2][4]) {
  int lane = threadIdx.x & 63;
  int r = lane & 15, g = lane >> 4;
  const u16* ap0 = A  + (size_t)(arow + r) * K + g * 8;
  const u16* bp0 = BT + (size_t)(bcol + r) * K + g * 8;
  #pragma unroll 4
  for (int k0 = 0; k0 < K; k0 += 32) {
    bf16x8 a0 = *bfp(ap0 + k0);
    bf16x8 a1 = *bfp(ap0 + 16 * K + k0);
    #pragma unroll
    for (int nt = 0; nt < 4; ++nt) {
      bf16x8 b = *bfp(bp0 + nt * 16 * K + k0);
      acc[0][nt] = MFMA16(a0, b, acc[0][nt]);
      acc[1][nt] = MFMA16(a1, b, acc[1][nt]);
    }
  }
}

// K2: QKV = ln1 @ WqkvT. 32 rows/wave (128 rows/block).
__global__ __launch_bounds__(256) void k_qkv(
    const u16* __restrict__ ln, const u16* __restrict__ wT,
    u16* __restrict__ q, u16* __restrict__ kf, u16* __restrict__ vf) {
  int w = threadIdx.x >> 6, lane = threadIdx.x & 63;
  int r16 = lane & 15, g4 = lane >> 4;
  int m0 = blockIdx.y * 128 + w * 32;
  int n0 = blockIdx.x * 64;
  f32x4 z = {0.f, 0.f, 0.f, 0.f};
  f32x4 acc[2][4] = {{z, z, z, z}, {z, z, z, z}};
  mm32<256>(ln, wT, m0, n0, acc);
  int b = m0 >> 12;
  const float qs = (float)(0.17677669529663687 * 1.4426950408889634);
  #pragma unroll
  for (int rg = 0; rg < 2; ++rg) {
    int nbase = (m0 & 4095) + rg * 16 + g4 * 4;
    #pragma unroll
    for (int nt = 0; nt < 4; ++nt) {
      int col = n0 + nt * 16 + r16;
      int which = col >> 8, h = (col >> 5) & 7, d = col & 31;
      size_t bh_off = ((size_t)(b * 8 + h)) << 17;
      if (which == 0) {
        #pragma unroll
        for (int r = 0; r < 4; ++r)
          q[((size_t)(b * 8 + h) * 4096 + nbase + r) * 32 + d] =
              f2bf(acc[rg][nt][r] * qs);
      } else if (which == 1) {
        int sel = d >> 4, lh = (d >> 3) & 1, jj = d & 7;
        #pragma unroll
        for (int r = 0; r < 4; ++r) {
          int key = nbase + r;
          kf[bh_off + (size_t)(key >> 5) * 1024 + sel * 512 +
             (((key & 31) | (lh << 5)) << 3) + jj] = f2bf(acc[rg][nt][r]);
        }
      } else {
        int kk = nbase & 31;
        int sel = kk >> 4, lh = (kk >> 3) & 1, j0 = kk & 7;
        ushort4 o4;
        o4.x = f2bf(acc[rg][nt][0]); o4.y = f2bf(acc[rg][nt][1]);
        o4.z = f2bf(acc[rg][nt][2]); o4.w = f2bf(acc[rg][nt][3]);
        *(ushort4*)(vf + bh_off + (size_t)(nbase >> 5) * 1024 + sel * 512 +
                    ((d | (lh << 5)) << 3) + j0) = o4;
      }
    }
  }
}

// ---------------------------------------------------------------------------
// K3: attention (best-measured R10 form, frozen). 1024 blocks, 512 thr =
// 2 q-subtiles(64 q) x 4 KV-quarters; XCD-locality remap; builtin exp2
// (trans pipe); VALU tree row-sum; two-round LDS 4-way combine.
__global__ __launch_bounds__(512, 4) void k_attn(
    const u16* __restrict__ q, const u16* __restrict__ kf,
    const u16* __restrict__ vf, u16* __restrict__ attnout) {
  __shared__ float obuf[2][3][64][17];
  __shared__ float lsbuf[2][3][64];
  int lane = threadIdx.x & 63;
  int w = threadIdx.x >> 6;
  int qi = w >> 2, kj = w & 3;
  int r32 = lane & 31, hi = lane >> 5;
  int d = blockIdx.x;
  int bh = (d & 7) + 8 * (d >> 8);
  int qt = (d >> 3) & 31;
  int q0 = qt * 128 + qi * 64;
  const u16* qh = q + ((size_t)bh << 17);
  bf16x8 qf00 = *bfp(qh + (size_t)(q0 + r32) * 32 + hi * 8);
  bf16x8 qf01 = *bfp(qh + (size_t)(q0 + r32) * 32 + 16 + hi * 8);
  bf16x8 qf10 = *bfp(qh + (size_t)(q0 + 32 + r32) * 32 + hi * 8);
  bf16x8 qf11 = *bfp(qh + (size_t)(q0 + 32 + r32) * 32 + 16 + hi * 8);

  const u16* kp = kf + ((size_t)bh << 17) + (size_t)kj * 32768 + lane * 8;
  const u16* vp = vf + ((size_t)bh << 17) + (size_t)kj * 32768 + lane * 8;

  f32x16 o0, o1, zz;
  #pragma unroll
  for (int r = 0; r < 16; ++r) { o0[r] = 0.f; o1[r] = 0.f; zz[r] = 0.f; }
  float ls0 = 0.f, ls1 = 0.f;

  #pragma unroll 2
  for (int c = 0; c < 32; ++c) {
    bf16x8 ka0 = *bfp(kp);
    bf16x8 ka1 = *bfp(kp + 512);
    bf16x8 va0 = *bfp(vp);
    bf16x8 va1 = *bfp(vp + 512);
    kp += 1024; vp += 1024;

    // ---- q-group 0
    {
      f32x16 s = MFMA32(ka0, qf00, zz);
      s = MFMA32(ka1, qf01, s);
      #pragma unroll
      for (int r = 0; r < 16; ++r) s[r] = __builtin_amdgcn_exp2f(s[r]);
      float t0 = ((s[0] + s[1]) + (s[2] + s[3])) + ((s[4] + s[5]) + (s[6] + s[7]));
      float t1 = ((s[8] + s[9]) + (s[10] + s[11])) + ((s[12] + s[13]) + (s[14] + s[15]));
      ls0 += t0 + t1;
      u32 c8[8];
      #pragma unroll
      for (int i = 0; i < 8; ++i)
        asm("v_cvt_pk_bf16_f32 %0, %1, %2" : "=v"(c8[i]) : "v"(s[2 * i]), "v"(s[2 * i + 1]));
      asm("v_permlane32_swap_b32 %0, %1" : "+v"(c8[0]), "+v"(c8[2]));
      asm("v_permlane32_swap_b32 %0, %1" : "+v"(c8[1]), "+v"(c8[3]));
      asm("v_permlane32_swap_b32 %0, %1" : "+v"(c8[4]), "+v"(c8[6]));
      asm("v_permlane32_swap_b32 %0, %1" : "+v"(c8[5]), "+v"(c8[7]));
      union { u32 u[4]; bf16x8 v; } pf0, pf1;
      pf0.u[0] = c8[0]; pf0.u[1] = c8[1]; pf0.u[2] = c8[2]; pf0.u[3] = c8[3];
      pf1.u[0] = c8[4]; pf1.u[1] = c8[5]; pf1.u[2] = c8[6]; pf1.u[3] = c8[7];
      o0 = MFMA32(va0, pf0.v, o0);
      o0 = MFMA32(va1, pf1.v, o0);
    }
    // ---- q-group 1
    {
      f32x16 s = MFMA32(ka0, qf10, zz);
      s = MFMA32(ka1, qf11, s);
      #pragma unroll
      for (int r = 0; r < 16; ++r) s[r] = __builtin_amdgcn_exp2f(s[r]);
      float t0 = ((s[0] + s[1]) + (s[2] + s[3])) + ((s[4] + s[5]) + (s[6] + s[7]));
      float t1 = ((s[8] + s[9]) + (s[10] + s[11])) + ((s[12] + s[13]) + (s[14] + s[15]));
      ls1 += t0 + t1;
      u32 c8[8];
      #pragma unroll
      for (int i = 0; i < 8; ++i)
        asm("v_cvt_pk_bf16_f32 %0, %1, %2" : "=v"(c8[i]) : "v"(s[2 * i]), "v"(s[2 * i + 1]));
      asm("v_permlane32_swap_b32 %0, %1" : "+v"(c8[0]), "+v"(c8[2]));
      asm("v_permlane32_swap_b32 %0, %1" : "+v"(c8[1]), "+v"(c8[3]));
      asm("v_permlane32_swap_b32 %0, %1" : "+v"(c8[4]), "+v"(c8[6]));
      asm("v_permlane32_swap_b32 %0, %1" : "+v"(c8[5]), "+v"(c8[7]));
      union { u32 u[4]; bf16x8 v; } pf0, pf1;
      pf0.u[0] = c8[0]; pf0.u[1] = c8[1]; pf0.u[2] = c8[2]; pf0.u[3] = c8[3];
      pf1.u[0] = c8[4]; pf1.u[1] = c8[5]; pf1.u[2] = c8[6]; pf1.u[3] = c8[7];
      o1 = MFMA32(va0, pf0.v, o1);
      o1 = MFMA32(va1, pf1.v, o1);
    }
  }

  ls0 += __shfl_xor(ls0, 32);
  ls1 += __shfl_xor(ls1, 32);

  if (kj != 0) {
    #pragma unroll
    for (int g = 0; g < 16; ++g) obuf[qi][kj - 1][lane][g] = o0[g];
    lsbuf[qi][kj - 1][lane] = ls0;
  }
  __syncthreads();
  float inv0 = 0.f;
  if (kj == 0) {
    float lst = ls0 + lsbuf[qi][0][lane] + lsbuf[qi][1][lane] + lsbuf[qi][2][lane];
    inv0 = __builtin_amdgcn_rcpf(lst);
    #pragma unroll
    for (int g = 0; g < 16; ++g)
      o0[g] += obuf[qi][0][lane][g] + obuf[qi][1][lane][g] + obuf[qi][2][lane][g];
  }
  __syncthreads();
  if (kj != 0) {
    #pragma unroll
    for (int g = 0; g < 16; ++g) obuf[qi][kj - 1][lane][g] = o1[g];
    lsbuf[qi][kj - 1][lane] = ls1;
  }
  __syncthreads();
  if (kj == 0) {
    int b = bh >> 3, h = bh & 7;
    float lst1 = ls1 + lsbuf[qi][0][lane] + lsbuf[qi][1][lane] + lsbuf[qi][2][lane];
    float inv1 = __builtin_amdgcn_rcpf(lst1);
    #pragma unroll
    for (int g = 0; g < 16; ++g)
      o1[g] += obuf[qi][0][lane][g] + obuf[qi][1][lane][g] + obuf[qi][2][lane][g];
    size_t nrow0 = ((size_t)(b * 4096 + q0 + r32)) * 256 + h * 32;
    size_t nrow1 = ((size_t)(b * 4096 + q0 + 32 + r32)) * 256 + h * 32;
    #pragma unroll
    for (int g = 0; g < 4; ++g) {
      ushort4 ov;
      ov.x = f2bf(o0[g * 4 + 0] * inv0);
      ov.y = f2bf(o0[g * 4 + 1] * inv0);
      ov.z = f2bf(o0[g * 4 + 2] * inv0);
      ov.w = f2bf(o0[g * 4 + 3] * inv0);
      *(ushort4*)(attnout + nrow0 + g * 8 + hi * 4) = ov;
      ushort4 ow;
      ow.x = f2bf(o1[g * 4 + 0] * inv1);
      ow.y = f2bf(o1[g * 4 + 1] * inv1);
      ow.z = f2bf(o1[g * 4 + 2] * inv1);
      ow.w = f2bf(o1[g * 4 + 3] * inv1);
      *(ushort4*)(attnout + nrow1 + g * 8 + hi * 4) = ow;
    }
  }
}

// ---------------------------------------------------------------------------
// K4: fused post-pass: proj+residual+LN2 -> MLP1+GELU -> MLP2+residual -> out.
// Block = 32 rows x 512 thr (8 waves: rh=w&1 row-half, cg=w>>1 col-group).
// tokens2 (post-residual) stays in registers between stage A and C (same
// (rh,cg) tile); ln2 and h live only in LDS.
__global__ __launch_bounds__(512) void k_post(
    const u16* __restrict__ ao, const u16* __restrict__ wpT,
    const float* __restrict__ bp, const float* __restrict__ g2,
    const float* __restrict__ b2, const float* __restrict__ tokens,
    const u16* __restrict__ w1T, const float* __restrict__ bf1,
    const u16* __restrict__ w2T, const float* __restrict__ bf2,
    float* __restrict__ out) {
  __shared__ u16 lnS[32][264];
  __shared__ u16 hS[32][520];
  __shared__ float red[2][2][4][16];
  int w = threadIdx.x >> 6, lane = threadIdx.x & 63;
  int r16 = lane & 15, g4 = lane >> 4;
  int rh = w & 1, cg = w >> 1;
  int m0 = blockIdx.x * 32;
  int row0 = m0 + rh * 16;

  // ---- stage A: proj + residual + LN2 (ln2 -> LDS, tokens2 -> regs)
  f32x4 z = {0.f, 0.f, 0.f, 0.f};
  f32x4 tA[4] = {z, z, z, z};
  mm16<256>(ao, wpT, row0, cg * 64, tA);
  float sum[4] = {0.f, 0.f, 0.f, 0.f}, sq[4] = {0.f, 0.f, 0.f, 0.f};
  #pragma unroll
  for (int nt = 0; nt < 4; ++nt) {
    int col = cg * 64 + nt * 16 + r16;
    float bias = bp[col];
    #pragma unroll
    for (int r = 0; r < 4; ++r) {
      float v = tokens[(size_t)(row0 + g4 * 4 + r) * 256 + col] + tA[nt][r] + bias;
      tA[nt][r] = v;
      sum[r] += v; sq[r] += v * v;
    }
  }
  #pragma unroll
  for (int mask = 1; mask < 16; mask <<= 1) {
    #pragma unroll
    for (int r = 0; r < 4; ++r) {
      sum[r] += __shfl_xor(sum[r], mask);
      sq[r]  += __shfl_xor(sq[r], mask);
    }
  }
  if (r16 == 0) {
    #pragma unroll
    for (int r = 0; r < 4; ++r) {
      red[0][rh][cg][g4 * 4 + r] = sum[r];
      red[1][rh][cg][g4 * 4 + r] = sq[r];
    }
  }
  __syncthreads();
  {
    float mu[4], rs[4];
    #pragma unroll
    for (int r = 0; r < 4; ++r) {
      int ri = g4 * 4 + r;
      float S  = red[0][rh][0][ri] + red[0][rh][1][ri] + red[0][rh][2][ri] + red[0][rh][3][ri];
      float SQ = red[1][rh][0][ri] + red[1][rh][1][ri] + red[1][rh][2][ri] + red[1][rh][3][ri];
      mu[r] = S * (1.f / 256.f);
      rs[r] = rsqrtf(SQ * (1.f / 256.f) - mu[r] * mu[r] + 1e-5f);
    }
    #pragma unroll
    for (int nt = 0; nt < 4; ++nt) {
      int col = cg * 64 + nt * 16 + r16;
      float gg = g2[col], bb = b2[col];
      #pragma unroll
      for (int r = 0; r < 4; ++r)
        lnS[rh * 16 + g4 * 4 + r][col] = f2bf((tA[nt][r] - mu[r]) * rs[r] * gg + bb);
    }
  }
  __syncthreads();

  // ---- stage B: h = gelu(ln2 @ W1T + bf1), 16 rows x 128 cols per wave
  {
    f32x4 accB[8] = {z, z, z, z, z, z, z, z};
    const u16* apB = &lnS[rh * 16 + r16][g4 * 8];
    const u16* bpB = w1T + (size_t)(cg * 128 + r16) * 256 + g4 * 8;
    #pragma unroll 2
    for (int k0 = 0; k0 < 256; k0 += 32) {
      bf16x8 a = *bfp(apB + k0);
      #pragma unroll
      for (int nt = 0; nt < 8; ++nt) {
        bf16x8 b = *bfp(bpB + nt * 16 * 256 + k0);
        accB[nt] = MFMA16(a, b, accB[nt]);
      }
    }
    int rl = rh * 16 + g4 * 4;
    #pragma unroll
    for (int nt = 0; nt < 8; ++nt) {
      int col = cg * 128 + nt * 16 + r16;
      float bias = bf1[col];
      #pragma unroll
      for (int r = 0; r < 4; ++r) {
        float xx = accB[nt][r] + bias;
        float x2 = xx * xx;
        float zt = xx * (2.3021188f + 0.10293855f * x2);
        float e  = __builtin_amdgcn_exp2f(zt);
        float ge = xx * (1.f - __builtin_amdgcn_rcpf(1.f + e));
        hS[rl + r][col] = f2bf(ge);
      }
    }
  }
  __syncthreads();

  // ---- stage C: out = tokens2 + h @ W2T + bf2 (transposed store)
  {
    f32x4 accC[4] = {z, z, z, z};
    const u16* apC = &hS[rh * 16 + r16][g4 * 8];
    const u16* bpC = w2T + (size_t)(cg * 64 + r16) * 512 + g4 * 8;
    #pragma unroll 4
    for (int k0 = 0; k0 < 512; k0 += 32) {
      bf16x8 a = *bfp(apC + k0);
      #pragma unroll
      for (int nt = 0; nt < 4; ++nt) {
        bf16x8 b = *bfp(bpC + nt * 16 * 512 + k0);
        accC[nt] = MFMA16(a, b, accC[nt]);
      }
    }
    int b = m0 >> 12;
    int nl = (m0 & 4095) + rh * 16 + g4 * 4;
    #pragma unroll
    for (int nt = 0; nt < 4; ++nt) {
      int col = cg * 64 + nt * 16 + r16;
      float bias = bf2[col];
      float4 o;
      o.x = tA[nt][0] + accC[nt][0] + bias;
      o.y = tA[nt][1] + accC[nt][1] + bias;
      o.z = tA[nt][2] + accC[nt][2] + bias;
      o.w = tA[nt][3] + accC[nt][3] + bias;
      *(float4*)(out + (((size_t)(b * 256 + col)) << 12) + nl) = o;
    }
  }
}

// ---------------------------------------------------------------------------
extern "C" void kernel_launch(void* const* d_in, const int* in_sizes, int n_in,
                              void* d_out, int out_size, void* d_ws, size_t ws_size,
                              hipStream_t stream) {
  (void)in_sizes; (void)n_in; (void)out_size; (void)ws_size;
  const float* x    = (const float*)d_in[0];
  const float* g1   = (const float*)d_in[1];
  const float* b1   = (const float*)d_in[2];
  const float* Wqkv = (const float*)d_in[3];
  const float* Wp   = (const float*)d_in[4];
  const float* bp   = (const float*)d_in[5];
  const float* g2   = (const float*)d_in[6];
  const float* b2   = (const float*)d_in[7];
  const float* W1   = (const float*)d_in[8];
  const float* bf1  = (const float*)d_in[9];
  const float* W2   = (const float*)d_in[10];
  const float* bf2  = (const float*)d_in[11];
  float* out = (float*)d_out;

  char* ws = (char*)d_ws;
  float* tokens = (float*)(ws);                  // 16,777,216 B
  u16* lnb      = (u16*)(ws + 16777216);         //  8,388,608 B (ln1)
  u16* qb       = (u16*)(ws + 25165824);         //  8,388,608 B
  u16* kfb      = (u16*)(ws + 33554432);         //  8,388,608 B (K fragments)
  u16* vfb      = (u16*)(ws + 41943040);         //  8,388,608 B (V fragments)
  u16* aob      = (u16*)(ws + 50331648);         //  8,388,608 B (attnout)
  u16* wqkvT    = (u16*)(ws + 67108864);         //    393,216 B
  u16* wpT      = (u16*)(ws + 67502080);         //    131,072 B
  u16* w1T      = (u16*)(ws + 67633152);         //    262,144 B
  u16* w2T      = (u16*)(ws + 67895296);         //    262,144 B

  k_pre  <<<1024, 256, 0, stream>>>(x, g1, b1, tokens, lnb,
                                    Wqkv, Wp, W1, W2, wqkvT, wpT, w1T, w2T);
  k_qkv  <<<dim3(12, 128), 256, 0, stream>>>(lnb, wqkvT, qb, kfb, vfb);
  k_attn <<<1024, 512, 0, stream>>>(qb, kfb, vfb, aob);
  k_post <<<512, 512, 0, stream>>>(aob, wpT, bp, g2, b2, tokens,
                                   w1T, bf1, w2T, bf2, out);
}

// Round 16
// 213.674 us; speedup vs baseline: 1.0438x; 1.0144x over previous
//
#include <hip/hip_runtime.h>

typedef unsigned short u16;
typedef unsigned int   u32;

using bf16x8 = __attribute__((ext_vector_type(8))) __bf16;
using f32x4  = __attribute__((ext_vector_type(4))) float;
using f32x16 = __attribute__((ext_vector_type(16))) float;

#define MFMA16(a, b, c) __builtin_amdgcn_mfma_f32_16x16x32_bf16((a), (b), (c), 0, 0, 0)
#define MFMA32(a, b, c) __builtin_amdgcn_mfma_f32_32x32x16_bf16((a), (b), (c), 0, 0, 0)

__device__ inline u16 f2bf(float f) {
  u32 x = __float_as_uint(f);
  return (u16)((x + 0x7FFFu + ((x >> 16) & 1u)) >> 16);
}

__device__ inline const bf16x8* bfp(const u16* p) {
  return reinterpret_cast<const bf16x8*>(p);
}

// ---------------------------------------------------------------------------
// K01: merged pre-pass. Blocks 0..511: LN1 (x -> ln, bf16; NO tokens copy —
// k_post reads the residual straight from x). Blocks 512..1023: weight
// transpose+convert to bf16 W^T.
__global__ __launch_bounds__(256) void k_pre(
    const float* __restrict__ x, const float* __restrict__ g1,
    const float* __restrict__ b1, u16* __restrict__ ln,
    const float* __restrict__ Wqkv, const float* __restrict__ Wp,
    const float* __restrict__ W1,   const float* __restrict__ W2,
    u16* __restrict__ wqkvT, u16* __restrict__ wpT,
    u16* __restrict__ w1T,   u16* __restrict__ w2T) {
  __shared__ float tile[256][33];
  __shared__ float red[2][8][32];
  __shared__ float stat[2][32];
  int tid = threadIdx.x;
  if (blockIdx.x >= 512) {
    int blk = blockIdx.x - 512;
    const float* src; u16* dst; int R, C, t;
    if (blk < 192)      { src = Wqkv; dst = wqkvT; R = 256; C = 768; t = blk; }
    else if (blk < 256) { src = Wp;   dst = wpT;   R = 256; C = 256; t = blk - 192; }
    else if (blk < 384) { src = W1;   dst = w1T;   R = 256; C = 512; t = blk - 256; }
    else                { src = W2;   dst = w2T;   R = 512; C = 256; t = blk - 384; }
    int tpc = C >> 5;
    int tr = (t / tpc) << 5, tc = (t % tpc) << 5;
    int j = tid & 31, iq = tid >> 5;
    #pragma unroll
    for (int i = 0; i < 4; ++i)
      tile[iq + 8 * i][j] = src[(size_t)(tr + iq + 8 * i) * C + tc + j];
    __syncthreads();
    #pragma unroll
    for (int i = 0; i < 4; ++i)
      dst[(size_t)(tc + iq + 8 * i) * R + tr + j] = f2bf(tile[j][iq + 8 * i]);
    return;
  }
  int blk = blockIdx.x;
  int b = blk >> 7, n0 = (blk & 127) << 5;
  {
    int cq = tid >> 5, j = tid & 31;
    const float* xp = x + (((size_t)b * 256) << 12) + n0 + j;
    #pragma unroll 8
    for (int it = 0; it < 32; ++it) {
      int c = it * 8 + cq;
      tile[c][j] = xp[(size_t)c << 12];
    }
  }
  __syncthreads();
  {
    int tn = tid & 31, qq = tid >> 5;
    float s = 0.f, s2 = 0.f;
    #pragma unroll 8
    for (int i = 0; i < 32; ++i) {
      float v = tile[qq * 32 + i][tn];
      s += v; s2 += v * v;
    }
    red[0][qq][tn] = s; red[1][qq][tn] = s2;
  }
  __syncthreads();
  if (tid < 32) {
    float su = 0.f, sq = 0.f;
    #pragma unroll
    for (int qq = 0; qq < 8; ++qq) { su += red[0][qq][tid]; sq += red[1][qq][tid]; }
    float mu  = su * (1.f / 256.f);
    float var = sq * (1.f / 256.f) - mu * mu;
    stat[0][tid] = mu;
    stat[1][tid] = rsqrtf(var + 1e-5f);
  }
  __syncthreads();
  float g = g1[tid], bb = b1[tid];
  size_t base = ((size_t)(b * 4096 + n0)) * 256 + tid;
  for (int it = 0; it < 32; ++it) {
    float v = tile[tid][it];
    float y = (v - stat[0][it]) * stat[1][it] * g + bb;
    ln[base + (size_t)it * 256] = f2bf(y);
  }
}

// ---------------------------------------------------------------------------
// GEMM cores. C[m][n] = sum_k A[m][k] * BT[n][k], both bf16 row-major.
template <int K>
__device__ inline void mm16(const u16* __restrict__ A, const u16* __restrict__ BT,
                            int arow, int bcol, f32x4 acc[4]) {
  int lane = threadIdx.x & 63;
  int r = lane & 15, g = lane >> 4;
  const u16* ap  = A  + (size_t)(arow + r) * K + g * 8;
  const u16* bp0 = BT + (size_t)(bcol + r) * K + g * 8;
  #pragma unroll 4
  for (int k0 = 0; k0 < K; k0 += 32) {
    bf16x8 a = *bfp(ap + k0);
    #pragma unroll
    for (int nt = 0; nt < 4; ++nt) {
      bf16x8 b = *bfp(bp0 + nt * 16 * K + k0);
      acc[nt] = MFMA16(a, b, acc[nt]);
    }
  }
}

// 32 rows/wave: shared B-frags, 8 MFMAs per 6 loads.
template <int K>
__device__ inline void mm32(const u16* __restrict__ A, const u16* __restrict__ BT,
                            int arow, int bcol, f32x4 acc[2][4]) {
  int lane = threadIdx.x & 63;
  int r = lane & 15, g = lane >> 4;
  const u16* ap0 = A  + (size_t)(arow + r) * K + g * 8;
  const u16* bp0 = BT + (size_t)(bcol + r) * K + g * 8;
  #pragma unroll 4
  for (int k0 = 0; k0 < K; k0 += 32) {
    bf16x8 a0 = *bfp(ap0 + k0);
    bf16x8 a1 = *bfp(ap0 + 16 * K + k0);
    #pragma unroll
    for (int nt = 0; nt < 4; ++nt) {
      bf16x8 b = *bfp(bp0 + nt * 16 * K + k0);
      acc[0][nt] = MFMA16(a0, b, acc[0][nt]);
      acc[1][nt] = MFMA16(a1, b, acc[1][nt]);
    }
  }
}

// K2: QKV = ln1 @ WqkvT. 32 rows/wave (128 rows/block).
__global__ __launch_bounds__(256) void k_qkv(
    const u16* __restrict__ ln, const u16* __restrict__ wT,
    u16* __restrict__ q, u16* __restrict__ kf, u16* __restrict__ vf) {
  int w = threadIdx.x >> 6, lane = threadIdx.x & 63;
  int r16 = lane & 15, g4 = lane >> 4;
  int m0 = blockIdx.y * 128 + w * 32;
  int n0 = blockIdx.x * 64;
  f32x4 z = {0.f, 0.f, 0.f, 0.f};
  f32x4 acc[2][4] = {{z, z, z, z}, {z, z, z, z}};
  mm32<256>(ln, wT, m0, n0, acc);
  int b = m0 >> 12;
  const float qs = (float)(0.17677669529663687 * 1.4426950408889634);
  #pragma unroll
  for (int rg = 0; rg < 2; ++rg) {
    int nbase = (m0 & 4095) + rg * 16 + g4 * 4;
    #pragma unroll
    for (int nt = 0; nt < 4; ++nt) {
      int col = n0 + nt * 16 + r16;
      int which = col >> 8, h = (col >> 5) & 7, d = col & 31;
      size_t bh_off = ((size_t)(b * 8 + h)) << 17;
      if (which == 0) {
        #pragma unroll
        for (int r = 0; r < 4; ++r)
          q[((size_t)(b * 8 + h) * 4096 + nbase + r) * 32 + d] =
              f2bf(acc[rg][nt][r] * qs);
      } else if (which == 1) {
        int sel = d >> 4, lh = (d >> 3) & 1, jj = d & 7;
        #pragma unroll
        for (int r = 0; r < 4; ++r) {
          int key = nbase + r;
          kf[bh_off + (size_t)(key >> 5) * 1024 + sel * 512 +
             (((key & 31) | (lh << 5)) << 3) + jj] = f2bf(acc[rg][nt][r]);
        }
      } else {
        int kk = nbase & 31;
        int sel = kk >> 4, lh = (kk >> 3) & 1, j0 = kk & 7;
        ushort4 o4;
        o4.x = f2bf(acc[rg][nt][0]); o4.y = f2bf(acc[rg][nt][1]);
        o4.z = f2bf(acc[rg][nt][2]); o4.w = f2bf(acc[rg][nt][3]);
        *(ushort4*)(vf + bh_off + (size_t)(nbase >> 5) * 1024 + sel * 512 +
                    ((d | (lh << 5)) << 3) + j0) = o4;
      }
    }
  }
}

// ---------------------------------------------------------------------------
// K3: attention (best-measured R10 form, frozen). 1024 blocks, 512 thr =
// 2 q-subtiles(64 q) x 4 KV-quarters; XCD-locality remap; builtin exp2
// (trans pipe); VALU tree row-sum; two-round LDS 4-way combine.
__global__ __launch_bounds__(512, 4) void k_attn(
    const u16* __restrict__ q, const u16* __restrict__ kf,
    const u16* __restrict__ vf, u16* __restrict__ attnout) {
  __shared__ float obuf[2][3][64][17];
  __shared__ float lsbuf[2][3][64];
  int lane = threadIdx.x & 63;
  int w = threadIdx.x >> 6;
  int qi = w >> 2, kj = w & 3;
  int r32 = lane & 31, hi = lane >> 5;
  int d = blockIdx.x;
  int bh = (d & 7) + 8 * (d >> 8);
  int qt = (d >> 3) & 31;
  int q0 = qt * 128 + qi * 64;
  const u16* qh = q + ((size_t)bh << 17);
  bf16x8 qf00 = *bfp(qh + (size_t)(q0 + r32) * 32 + hi * 8);
  bf16x8 qf01 = *bfp(qh + (size_t)(q0 + r32) * 32 + 16 + hi * 8);
  bf16x8 qf10 = *bfp(qh + (size_t)(q0 + 32 + r32) * 32 + hi * 8);
  bf16x8 qf11 = *bfp(qh + (size_t)(q0 + 32 + r32) * 32 + 16 + hi * 8);

  const u16* kp = kf + ((size_t)bh << 17) + (size_t)kj * 32768 + lane * 8;
  const u16* vp = vf + ((size_t)bh << 17) + (size_t)kj * 32768 + lane * 8;

  f32x16 o0, o1, zz;
  #pragma unroll
  for (int r = 0; r < 16; ++r) { o0[r] = 0.f; o1[r] = 0.f; zz[r] = 0.f; }
  float ls0 = 0.f, ls1 = 0.f;

  #pragma unroll 2
  for (int c = 0; c < 32; ++c) {
    bf16x8 ka0 = *bfp(kp);
    bf16x8 ka1 = *bfp(kp + 512);
    bf16x8 va0 = *bfp(vp);
    bf16x8 va1 = *bfp(vp + 512);
    kp += 1024; vp += 1024;

    // ---- q-group 0
    {
      f32x16 s = MFMA32(ka0, qf00, zz);
      s = MFMA32(ka1, qf01, s);
      #pragma unroll
      for (int r = 0; r < 16; ++r) s[r] = __builtin_amdgcn_exp2f(s[r]);
      float t0 = ((s[0] + s[1]) + (s[2] + s[3])) + ((s[4] + s[5]) + (s[6] + s[7]));
      float t1 = ((s[8] + s[9]) + (s[10] + s[11])) + ((s[12] + s[13]) + (s[14] + s[15]));
      ls0 += t0 + t1;
      u32 c8[8];
      #pragma unroll
      for (int i = 0; i < 8; ++i)
        asm("v_cvt_pk_bf16_f32 %0, %1, %2" : "=v"(c8[i]) : "v"(s[2 * i]), "v"(s[2 * i + 1]));
      asm("v_permlane32_swap_b32 %0, %1" : "+v"(c8[0]), "+v"(c8[2]));
      asm("v_permlane32_swap_b32 %0, %1" : "+v"(c8[1]), "+v"(c8[3]));
      asm("v_permlane32_swap_b32 %0, %1" : "+v"(c8[4]), "+v"(c8[6]));
      asm("v_permlane32_swap_b32 %0, %1" : "+v"(c8[5]), "+v"(c8[7]));
      union { u32 u[4]; bf16x8 v; } pf0, pf1;
      pf0.u[0] = c8[0]; pf0.u[1] = c8[1]; pf0.u[2] = c8[2]; pf0.u[3] = c8[3];
      pf1.u[0] = c8[4]; pf1.u[1] = c8[5]; pf1.u[2] = c8[6]; pf1.u[3] = c8[7];
      o0 = MFMA32(va0, pf0.v, o0);
      o0 = MFMA32(va1, pf1.v, o0);
    }
    // ---- q-group 1
    {
      f32x16 s = MFMA32(ka0, qf10, zz);
      s = MFMA32(ka1, qf11, s);
      #pragma unroll
      for (int r = 0; r < 16; ++r) s[r] = __builtin_amdgcn_exp2f(s[r]);
      float t0 = ((s[0] + s[1]) + (s[2] + s[3])) + ((s[4] + s[5]) + (s[6] + s[7]));
      float t1 = ((s[8] + s[9]) + (s[10] + s[11])) + ((s[12] + s[13]) + (s[14] + s[15]));
      ls1 += t0 + t1;
      u32 c8[8];
      #pragma unroll
      for (int i = 0; i < 8; ++i)
        asm("v_cvt_pk_bf16_f32 %0, %1, %2" : "=v"(c8[i]) : "v"(s[2 * i]), "v"(s[2 * i + 1]));
      asm("v_permlane32_swap_b32 %0, %1" : "+v"(c8[0]), "+v"(c8[2]));
      asm("v_permlane32_swap_b32 %0, %1" : "+v"(c8[1]), "+v"(c8[3]));
      asm("v_permlane32_swap_b32 %0, %1" : "+v"(c8[4]), "+v"(c8[6]));
      asm("v_permlane32_swap_b32 %0, %1" : "+v"(c8[5]), "+v"(c8[7]));
      union { u32 u[4]; bf16x8 v; } pf0, pf1;
      pf0.u[0] = c8[0]; pf0.u[1] = c8[1]; pf0.u[2] = c8[2]; pf0.u[3] = c8[3];
      pf1.u[0] = c8[4]; pf1.u[1] = c8[5]; pf1.u[2] = c8[6]; pf1.u[3] = c8[7];
      o1 = MFMA32(va0, pf0.v, o1);
      o1 = MFMA32(va1, pf1.v, o1);
    }
  }

  ls0 += __shfl_xor(ls0, 32);
  ls1 += __shfl_xor(ls1, 32);

  if (kj != 0) {
    #pragma unroll
    for (int g = 0; g < 16; ++g) obuf[qi][kj - 1][lane][g] = o0[g];
    lsbuf[qi][kj - 1][lane] = ls0;
  }
  __syncthreads();
  float inv0 = 0.f;
  if (kj == 0) {
    float lst = ls0 + lsbuf[qi][0][lane] + lsbuf[qi][1][lane] + lsbuf[qi][2][lane];
    inv0 = __builtin_amdgcn_rcpf(lst);
    #pragma unroll
    for (int g = 0; g < 16; ++g)
      o0[g] += obuf[qi][0][lane][g] + obuf[qi][1][lane][g] + obuf[qi][2][lane][g];
  }
  __syncthreads();
  if (kj != 0) {
    #pragma unroll
    for (int g = 0; g < 16; ++g) obuf[qi][kj - 1][lane][g] = o1[g];
    lsbuf[qi][kj - 1][lane] = ls1;
  }
  __syncthreads();
  if (kj == 0) {
    int b = bh >> 3, h = bh & 7;
    float lst1 = ls1 + lsbuf[qi][0][lane] + lsbuf[qi][1][lane] + lsbuf[qi][2][lane];
    float inv1 = __builtin_amdgcn_rcpf(lst1);
    #pragma unroll
    for (int g = 0; g < 16; ++g)
      o1[g] += obuf[qi][0][lane][g] + obuf[qi][1][lane][g] + obuf[qi][2][lane][g];
    size_t nrow0 = ((size_t)(b * 4096 + q0 + r32)) * 256 + h * 32;
    size_t nrow1 = ((size_t)(b * 4096 + q0 + 32 + r32)) * 256 + h * 32;
    #pragma unroll
    for (int g = 0; g < 4; ++g) {
      ushort4 ov;
      ov.x = f2bf(o0[g * 4 + 0] * inv0);
      ov.y = f2bf(o0[g * 4 + 1] * inv0);
      ov.z = f2bf(o0[g * 4 + 2] * inv0);
      ov.w = f2bf(o0[g * 4 + 3] * inv0);
      *(ushort4*)(attnout + nrow0 + g * 8 + hi * 4) = ov;
      ushort4 ow;
      ow.x = f2bf(o1[g * 4 + 0] * inv1);
      ow.y = f2bf(o1[g * 4 + 1] * inv1);
      ow.z = f2bf(o1[g * 4 + 2] * inv1);
      ow.w = f2bf(o1[g * 4 + 3] * inv1);
      *(ushort4*)(attnout + nrow1 + g * 8 + hi * 4) = ow;
    }
  }
}

// ---------------------------------------------------------------------------
// K4: fused post-pass: proj+residual+LN2 -> MLP1+GELU -> MLP2+residual -> out.
// Block = 32 rows x 512 thr (8 waves: rh=w&1 row-half, cg=w>>1 col-group).
// Residual read DIRECTLY from x (x[b][col][n..n+3] == tokens[n..n+3][col],
// contiguous float4 — tokens buffer eliminated). tokens2 stays in registers
// between stage A and C; ln2 and h live only in LDS.
__global__ __launch_bounds__(512) void k_post(
    const u16* __restrict__ ao, const u16* __restrict__ wpT,
    const float* __restrict__ bp, const float* __restrict__ g2,
    const float* __restrict__ b2, const float* __restrict__ xres,
    const u16* __restrict__ w1T, const float* __restrict__ bf1,
    const u16* __restrict__ w2T, const float* __restrict__ bf2,
    float* __restrict__ out) {
  __shared__ u16 lnS[32][264];
  __shared__ u16 hS[32][520];
  __shared__ float red[2][2][4][16];
  int w = threadIdx.x >> 6, lane = threadIdx.x & 63;
  int r16 = lane & 15, g4 = lane >> 4;
  int rh = w & 1, cg = w >> 1;
  int m0 = blockIdx.x * 32;
  int row0 = m0 + rh * 16;
  int b = m0 >> 12;
  int nl = (m0 & 4095) + rh * 16 + g4 * 4;   // local n of this thread's 4 rows

  // ---- stage A: proj + residual(from x) + LN2 (ln2 -> LDS, tokens2 -> regs)
  f32x4 z = {0.f, 0.f, 0.f, 0.f};
  f32x4 tA[4] = {z, z, z, z};
  mm16<256>(ao, wpT, row0, cg * 64, tA);
  float sum[4] = {0.f, 0.f, 0.f, 0.f}, sq[4] = {0.f, 0.f, 0.f, 0.f};
  #pragma unroll
  for (int nt = 0; nt < 4; ++nt) {
    int col = cg * 64 + nt * 16 + r16;
    float bias = bp[col];
    float4 xr = *(const float4*)(xres + (((size_t)(b * 256 + col)) << 12) + nl);
    float vv[4] = {xr.x, xr.y, xr.z, xr.w};
    #pragma unroll
    for (int r = 0; r < 4; ++r) {
      float v = vv[r] + tA[nt][r] + bias;
      tA[nt][r] = v;
      sum[r] += v; sq[r] += v * v;
    }
  }
  #pragma unroll
  for (int mask = 1; mask < 16; mask <<= 1) {
    #pragma unroll
    for (int r = 0; r < 4; ++r) {
      sum[r] += __shfl_xor(sum[r], mask);
      sq[r]  += __shfl_xor(sq[r], mask);
    }
  }
  if (r16 == 0) {
    #pragma unroll
    for (int r = 0; r < 4; ++r) {
      red[0][rh][cg][g4 * 4 + r] = sum[r];
      red[1][rh][cg][g4 * 4 + r] = sq[r];
    }
  }
  __syncthreads();
  {
    float mu[4], rs[4];
    #pragma unroll
    for (int r = 0; r < 4; ++r) {
      int ri = g4 * 4 + r;
      float S  = red[0][rh][0][ri] + red[0][rh][1][ri] + red[0][rh][2][ri] + red[0][rh][3][ri];
      float SQ = red[1][rh][0][ri] + red[1][rh][1][ri] + red[1][rh][2][ri] + red[1][rh][3][ri];
      mu[r] = S * (1.f / 256.f);
      rs[r] = rsqrtf(SQ * (1.f / 256.f) - mu[r] * mu[r] + 1e-5f);
    }
    #pragma unroll
    for (int nt = 0; nt < 4; ++nt) {
      int col = cg * 64 + nt * 16 + r16;
      float gg = g2[col], bb = b2[col];
      #pragma unroll
      for (int r = 0; r < 4; ++r)
        lnS[rh * 16 + g4 * 4 + r][col] = f2bf((tA[nt][r] - mu[r]) * rs[r] * gg + bb);
    }
  }
  __syncthreads();

  // ---- stage B: h = gelu(ln2 @ W1T + bf1), 16 rows x 128 cols per wave
  {
    f32x4 accB[8] = {z, z, z, z, z, z, z, z};
    const u16* apB = &lnS[rh * 16 + r16][g4 * 8];
    const u16* bpB = w1T + (size_t)(cg * 128 + r16) * 256 + g4 * 8;
    #pragma unroll 2
    for (int k0 = 0; k0 < 256; k0 += 32) {
      bf16x8 a = *bfp(apB + k0);
      #pragma unroll
      for (int nt = 0; nt < 8; ++nt) {
        bf16x8 b = *bfp(bpB + nt * 16 * 256 + k0);
        accB[nt] = MFMA16(a, b, accB[nt]);
      }
    }
    int rl = rh * 16 + g4 * 4;
    #pragma unroll
    for (int nt = 0; nt < 8; ++nt) {
      int col = cg * 128 + nt * 16 + r16;
      float bias = bf1[col];
      #pragma unroll
      for (int r = 0; r < 4; ++r) {
        float xx = accB[nt][r] + bias;
        float x2 = xx * xx;
        float zt = xx * (2.3021188f + 0.10293855f * x2);
        float e  = __builtin_amdgcn_exp2f(zt);
        float ge = xx * (1.f - __builtin_amdgcn_rcpf(1.f + e));
        hS[rl + r][col] = f2bf(ge);
      }
    }
  }
  __syncthreads();

  // ---- stage C: out = tokens2 + h @ W2T + bf2 (transposed store)
  {
    f32x4 accC[4] = {z, z, z, z};
    const u16* apC = &hS[rh * 16 + r16][g4 * 8];
    const u16* bpC = w2T + (size_t)(cg * 64 + r16) * 512 + g4 * 8;
    #pragma unroll 4
    for (int k0 = 0; k0 < 512; k0 += 32) {
      bf16x8 a = *bfp(apC + k0);
      #pragma unroll
      for (int nt = 0; nt < 4; ++nt) {
        bf16x8 b = *bfp(bpC + nt * 16 * 512 + k0);
        accC[nt] = MFMA16(a, b, accC[nt]);
      }
    }
    #pragma unroll
    for (int nt = 0; nt < 4; ++nt) {
      int col = cg * 64 + nt * 16 + r16;
      float bias = bf2[col];
      float4 o;
      o.x = tA[nt][0] + accC[nt][0] + bias;
      o.y = tA[nt][1] + accC[nt][1] + bias;
      o.z = tA[nt][2] + accC[nt][2] + bias;
      o.w = tA[nt][3] + accC[nt][3] + bias;
      *(float4*)(out + (((size_t)(b * 256 + col)) << 12) + nl) = o;
    }
  }
}

// ---------------------------------------------------------------------------
extern "C" void kernel_launch(void* const* d_in, const int* in_sizes, int n_in,
                              void* d_out, int out_size, void* d_ws, size_t ws_size,
                              hipStream_t stream) {
  (void)in_sizes; (void)n_in; (void)out_size; (void)ws_size;
  const float* x    = (const float*)d_in[0];
  const float* g1   = (const float*)d_in[1];
  const float* b1   = (const float*)d_in[2];
  const float* Wqkv = (const float*)d_in[3];
  const float* Wp   = (const float*)d_in[4];
  const float* bp   = (const float*)d_in[5];
  const float* g2   = (const float*)d_in[6];
  const float* b2   = (const float*)d_in[7];
  const float* W1   = (const float*)d_in[8];
  const float* bf1  = (const float*)d_in[9];
  const float* W2   = (const float*)d_in[10];
  const float* bf2  = (const float*)d_in[11];
  float* out = (float*)d_out;

  char* ws = (char*)d_ws;
  u16* lnb      = (u16*)(ws + 16777216);         //  8,388,608 B (ln1)
  u16* qb       = (u16*)(ws + 25165824);         //  8,388,608 B
  u16* kfb      = (u16*)(ws + 33554432);         //  8,388,608 B (K fragments)
  u16* vfb      = (u16*)(ws + 41943040);         //  8,388,608 B (V fragments)
  u16* aob      = (u16*)(ws + 50331648);         //  8,388,608 B (attnout)
  u16* wqkvT    = (u16*)(ws + 67108864);         //    393,216 B
  u16* wpT      = (u16*)(ws + 67502080);         //    131,072 B
  u16* w1T      = (u16*)(ws + 67633152);         //    262,144 B
  u16* w2T      = (u16*)(ws + 67895296);         //    262,144 B

  k_pre  <<<1024, 256, 0, stream>>>(x, g1, b1, lnb,
                                    Wqkv, Wp, W1, W2, wqkvT, wpT, w1T, w2T);
  k_qkv  <<<dim3(12, 128), 256, 0, stream>>>(lnb, wqkvT, qb, kfb, vfb);
  k_attn <<<1024, 512, 0, stream>>>(qb, kfb, vfb, aob);
  k_post <<<512, 512, 0, stream>>>(aob, wpT, bp, g2, b2, x,
                                   w1T, bf1, w2T, bf2, out);
}